// Round 10
// baseline (191.835 us; speedup 1.0000x reference)
//
#include <hip/hip_runtime.h>
#include <cstdint>
#include <cstddef>

// Problem constants
#define SEQ   2048
#define BATCH 2
#define EMB   1024
#define NH    16
#define HD    64
#define MTOT  (BATCH * SEQ)   // 4096 rows
#define NX    (MTOT * EMB)    // 4,194,304
#define NW    (EMB * EMB)     // 1,048,576
#define QS    3072            // fused qkv row stride

typedef __bf16 bf16_t;
typedef __bf16 bf16x2 __attribute__((ext_vector_type(2)));
typedef __bf16 bf16x4 __attribute__((ext_vector_type(4)));
typedef __bf16 bf16x8 __attribute__((ext_vector_type(8)));
typedef float  f32x16 __attribute__((ext_vector_type(16)));

typedef __attribute__((address_space(1))) const void* as1cv;
typedef __attribute__((address_space(3))) void*       as3v;

__device__ __forceinline__ void async_cp16(const void* g, void* l) {
  __builtin_amdgcn_global_load_lds((as1cv)g, (as3v)l, 16, 0, 0);
}

__device__ __forceinline__ f32x16 mfma32(bf16x8 a, bf16x8 b, f32x16 c) {
  return __builtin_amdgcn_mfma_f32_32x32x16_bf16(a, b, c, 0, 0, 0);
}

__device__ __forceinline__ uint32_t pk2(float a, float b) {
  bf16x2 t; t[0] = (bf16_t)a; t[1] = (bf16_t)b;
  return __builtin_bit_cast(uint32_t, t);
}
__device__ __forceinline__ bf16x8 mk_frag(uint32_t x, uint32_t y,
                                          uint32_t z, uint32_t w) {
  uint4 u; u.x = x; u.y = y; u.z = z; u.w = w;
  return __builtin_bit_cast(bf16x8, u);
}

// ---------------------------------------------------------------- convert
__global__ __launch_bounds__(256) void cvt_all(
    const float* __restrict__ x,  const float* __restrict__ wq,
    const float* __restrict__ wk, const float* __restrict__ wv,
    const float* __restrict__ wo,
    bf16_t* __restrict__ xb,  bf16_t* __restrict__ wqb,
    bf16_t* __restrict__ wkb, bf16_t* __restrict__ wvb,
    bf16_t* __restrict__ wob) {
  long e = ((long)blockIdx.x * 256 + threadIdx.x) * 4;
  const float* s; bf16_t* d; long off;
  if (e < NX) { s = x; d = xb; off = e; }
  else {
    long e2 = e - NX;
    int w = (int)(e2 >> 20);          // NW == 2^20
    off = e2 & (NW - 1);
    s = (w == 0) ? wq : (w == 1) ? wk : (w == 2) ? wv : wo;
    d = (w == 0) ? wqb : (w == 1) ? wkb : (w == 2) ? wvb : wob;
  }
  float4 v = *(const float4*)(s + off);
  bf16x4 o;
  o[0] = (bf16_t)v.x; o[1] = (bf16_t)v.y; o[2] = (bf16_t)v.z; o[3] = (bf16_t)v.w;
  *(bf16x4*)(d + off) = o;
}

// ---------------------------------------------------------------- V transpose
__global__ __launch_bounds__(256) void vtrans(const bf16_t* __restrict__ QKV,
                                              bf16_t* __restrict__ VT) {
  const int hb = blockIdx.x;   // (b,h)
  const int sb = blockIdx.y;   // 64-row s-block
  const int h = hb & 15, b = hb >> 4;
  const int t = threadIdx.x;
  __shared__ __align__(16) bf16_t Ts[64 * 72];
  const bf16_t* Vp = QKV + ((size_t)(b * SEQ + sb * 64)) * QS + 2048 + h * HD;
  const int sr = t >> 4, d0 = (t & 15) * 4;
#pragma unroll
  for (int i = 0; i < 4; ++i) {
    bf16x4 v = *(const bf16x4*)(Vp + (size_t)(sr + 16 * i) * QS + d0);
    *(bf16x4*)&Ts[(sr + 16 * i) * 72 + d0] = v;
  }
  __syncthreads();
  const int d = t >> 2, tc = (t & 3) * 16;
  __align__(16) bf16_t out[16];
#pragma unroll
  for (int j = 0; j < 16; ++j) out[j] = Ts[(tc + j) * 72 + d];
  bf16_t* dst = VT + ((size_t)hb * HD + d) * SEQ + sb * 64 + tc;
  *(uint4*)(dst)     = *(uint4*)&out[0];
  *(uint4*)(dst + 8) = *(uint4*)&out[8];
}

// ---------------------------------------------------------------- GEMM
// C[M,NT] = A[M,K] * B[NT,K]^T + bias, C row stride CS. BMxBN tile, 4 waves
// 2x2, mfma32 register blocking. BK=64 XOR-swizzled global_load_lds staging.
// outproj uses 64x64 (1024 blocks, 4/CU): the GEMM regime is latency-bound
// (LDS only ~35% busy at 2-3 blocks/CU), so occupancy beats LDS-ratio.
template <typename OT, int BM, int BN, int CS>
__global__ __launch_bounds__(256) void gemm_f(
    const bf16_t* __restrict__ A, const bf16_t* __restrict__ Bw,
    const float* __restrict__ b0, const float* __restrict__ b1,
    const float* __restrict__ b2, OT* __restrict__ C) {
  constexpr int K = EMB, BK = 64;
  __shared__ __align__(16) bf16_t As[BM * BK];
  __shared__ __align__(16) bf16_t Bs[BN * BK];

  const int tid  = threadIdx.x;
  const int lane = tid & 63;
  const int wave = tid >> 6;
  const int l31  = lane & 31;
  const int hi   = lane >> 5;
  const int wm   = (wave >> 1) * (BM / 2);
  const int wn   = (wave & 1) * (BN / 2);
  const int m0   = blockIdx.y * BM;
  const int n0   = blockIdx.x * BN;

  const float* bias = (n0 < 1024) ? b0 : ((n0 < 2048) ? b1 : b2);

  const int row0 = tid >> 3, slot = tid & 7;
  const bf16_t* gA[BM / 32];
  const bf16_t* gB[BN / 32];
#pragma unroll
  for (int i = 0; i < BM / 32; ++i)
    gA[i] = A + (size_t)(m0 + row0 + 32 * i) * K + (slot ^ (row0 & 7)) * 8;
#pragma unroll
  for (int i = 0; i < BN / 32; ++i)
    gB[i] = Bw + (size_t)(n0 + row0 + 32 * i) * K + (slot ^ (row0 & 7)) * 8;

  f32x16 acc[BM / 64][BN / 64] = {};
  const int sw = l31 & 7;   // frag-read unswizzle (row&7 == l31&7)

  for (int kk = 0; kk < K; kk += BK) {
#pragma unroll
    for (int i = 0; i < BM / 32; ++i)
      async_cp16(gA[i] + kk, &As[(tid + 256 * i) * 8]);
#pragma unroll
    for (int i = 0; i < BN / 32; ++i)
      async_cp16(gB[i] + kk, &Bs[(tid + 256 * i) * 8]);
    __syncthreads();

#pragma unroll
    for (int ks = 0; ks < 4; ++ks) {   // 4 k-steps of 16
      const int js = ((ks * 2 + hi) ^ sw) * 8;
      bf16x8 af[BM / 64], bfr[BN / 64];
#pragma unroll
      for (int i = 0; i < BM / 64; ++i)
        af[i] = *(const bf16x8*)&As[(wm + i * 32 + l31) * BK + js];
#pragma unroll
      for (int j = 0; j < BN / 64; ++j)
        bfr[j] = *(const bf16x8*)&Bs[(wn + j * 32 + l31) * BK + js];
#pragma unroll
      for (int i = 0; i < BM / 64; ++i)
#pragma unroll
        for (int j = 0; j < BN / 64; ++j)
          acc[i][j] = mfma32(af[i], bfr[j], acc[i][j]);
    }
    __syncthreads();
  }

#pragma unroll
  for (int i = 0; i < BM / 64; ++i)
#pragma unroll
    for (int j = 0; j < BN / 64; ++j) {
      const int col = n0 + wn + j * 32 + l31;
      const float bv = bias[col & 1023];
#pragma unroll
      for (int r = 0; r < 16; ++r) {
        const int row = m0 + wm + i * 32 + (r & 3) + 8 * (r >> 2) + 4 * hi;
        C[(size_t)row * CS + col] = (OT)(acc[i][j][r] + bv);
      }
    }
}

// ---------------------------------------------------------------- attention
// Flash attention, causal, S^T formulation, PARITY SPLIT-K for uniform load:
// block (hb, y, par) processes supertiles y and 15-y, key-tiles kt≡par (mod 2)
// only -> every block does exactly 17 iterations (512 blocks, 2/CU, zero
// tail). Fixed-max softmax makes split-K linear: unnormalized O partial (bf16)
// + l partial (fp32) per parity; combine kernel sums and normalizes.
// Only the final iter of each phase needs the causal mask.
__global__ __launch_bounds__(256, 3) void attn128(
    const bf16_t* __restrict__ QKVg, const bf16_t* __restrict__ VTg,
    bf16_t* __restrict__ Oe, bf16_t* __restrict__ Oo,
    float* __restrict__ Lg) {
  const int hb  = blockIdx.x;       // (b,h): pins to XCD hb%8
  const int y   = blockIdx.y;       // 0..7
  const int par = blockIdx.z;       // 0,1: key-tile parity
  const int h   = hb & 15, b = hb >> 4;
  const int tid = threadIdx.x;
  const int lane = tid & 63, wave = tid >> 6;
  const int l31 = lane & 31, hi = lane >> 5;
  const bool h0 = (hi == 0);

  __shared__ __align__(16) bf16_t Ks[2][64 * 72];
  __shared__ __align__(16) bf16_t VsT[2][64 * 72];   // [d][t]
  __shared__ __align__(16) bf16_t Qs[128 * 64];      // Q stage / O^T bounce

  const size_t base = ((size_t)b * SEQ) * QS + (size_t)h * HD;
  const bf16_t* Qb  = QKVg + base;          // Q at col offset 0
  const bf16_t* Kp  = QKVg + base + 1024;   // K at col offset 1024
  const bf16_t* VTp = VTg + (size_t)hb * HD * SEQ;
  bf16_t* Opar = par ? Oo : Oe;
  float*  Lp   = Lg + par * (32 * 2048) + hb * 2048;

  const int kr0r = tid >> 3, kcol = (tid & 7) * 8;
  const int kr1r = kr0r + 32;
  const int lo0 = kr0r * 72 + kcol;
  const int lo1 = lo0 + 32 * 72;

  for (int ph = 0; ph < 2; ++ph) {
    const int s   = ph ? (15 - y) : y;
    const int q0  = s * 128;
    const int n   = s + 1;              // parity tiles: kt = par, par+2, ...
    const bf16_t* Qp = Qb + (size_t)q0 * QS;

    // prefetch first K/V tile (kt = par)
    uint4 kr0 = *(const uint4*)(Kp + (size_t)(par * 64 + kr0r) * QS + kcol);
    uint4 kr1 = *(const uint4*)(Kp + (size_t)(par * 64 + kr1r) * QS + kcol);
    uint4 vr0 = *(const uint4*)(VTp + (size_t)kr0r * SEQ + par * 64 + kcol);
    uint4 vr1 = *(const uint4*)(VTp + (size_t)kr1r * SEQ + par * 64 + kcol);

    __syncthreads();   // phase 2: prior epilogue readers of Qs done
#pragma unroll
    for (int i = 0; i < 4; ++i) {   // stage Q: 1024 x 16B chunks, stride 64
      const int c = tid + 256 * i;
      *(uint4*)&Qs[(c >> 3) * 64 + (c & 7) * 8] =
          *(const uint4*)(Qp + (size_t)(c >> 3) * QS + (c & 7) * 8);
    }
    __syncthreads();

    bf16x8 qf[4];
#pragma unroll
    for (int kk = 0; kk < 4; ++kk)
      qf[kk] = *(const bf16x8*)&Qs[(32 * wave + l31) * 64 + kk * 16 + hi * 8];

    f32x16 acc_t0 = {}, acc_t1 = {};   // O^T partial: rows = d, col = q
    float lsum = 0.f;

    for (int it = 0; it < n; ++it) {
      const int kt = par + 2 * it;
      bf16_t* Kc = &Ks[it & 1][0];
      bf16_t* Vc = &VsT[it & 1][0];
      *(uint4*)&Kc[lo0] = kr0;
      *(uint4*)&Kc[lo1] = kr1;
      *(uint4*)&Vc[lo0] = vr0;
      *(uint4*)&Vc[lo1] = vr1;
      __syncthreads();

      if (it + 1 < n) {   // prefetch tile kt+2 under compute
        const bf16_t* Kn  = Kp + (size_t)(kt + 2) * 64 * QS;
        const bf16_t* VTn = VTp + (kt + 2) * 64;
        kr0 = *(const uint4*)(Kn + (size_t)kr0r * QS + kcol);
        kr1 = *(const uint4*)(Kn + (size_t)kr1r * QS + kcol);
        vr0 = *(const uint4*)(VTn + (size_t)kr0r * SEQ + kcol);
        vr1 = *(const uint4*)(VTn + (size_t)kr1r * SEQ + kcol);
      }

      // odd-parity final tile: waves 0,1 see only future keys -> skip
      const bool active = (64 * kt <= q0 + 32 * wave + 31);
      if (active) {
        // S^T = K Q^T : rows = 64 keys, cols = 32 q
        f32x16 s0 = {}, s1 = {};
#pragma unroll
        for (int kk = 0; kk < 4; ++kk) {
          const bf16x8 kf0 = *(const bf16x8*)&Kc[l31 * 72 + kk * 16 + hi * 8];
          const bf16x8 kf1 =
              *(const bf16x8*)&Kc[(32 + l31) * 72 + kk * 16 + hi * 8];
          s0 = mfma32(kf0, qf[kk], s0);
          s1 = mfma32(kf1, qf[kk], s1);
        }

        constexpr float SC2 = 0.18033688011112042f;  // (1/8) * log2(e)
        if (it == n - 1) {   // the only possibly-masked tile of this phase
          const int qg = q0 + 32 * wave + l31;
          const int k0 = 64 * kt + 4 * hi;
#pragma unroll
          for (int r = 0; r < 16; ++r) {
            const int key = k0 + (r & 3) + 8 * (r >> 2);
            float p0 = exp2f(__builtin_fmaf(s0[r], SC2, -8.f));
            float p1 = exp2f(__builtin_fmaf(s1[r], SC2, -8.f));
            if (key > qg) p0 = 0.f;
            if (key + 32 > qg) p1 = 0.f;
            s0[r] = p0; s1[r] = p1;
            lsum += p0 + p1;
          }
        } else {
#pragma unroll
          for (int r = 0; r < 16; ++r) {
            const float p0 = exp2f(__builtin_fmaf(s0[r], SC2, -8.f));
            const float p1 = exp2f(__builtin_fmaf(s1[r], SC2, -8.f));
            s0[r] = p0; s1[r] = p1;
            lsum += p0 + p1;
          }
        }

        // P^T -> B-operand frags via lane-32 register exchange
        bf16x8 pf[4];
#pragma unroll
        for (int kk = 0; kk < 4; ++kk) {
          const f32x16& g = (kk < 2) ? s0 : s1;
          const int bir = 8 * (kk & 1);
          const uint32_t PL0 = pk2(g[bir + 0], g[bir + 1]);
          const uint32_t PL1 = pk2(g[bir + 2], g[bir + 3]);
          const uint32_t PH0 = pk2(g[bir + 4], g[bir + 5]);
          const uint32_t PH1 = pk2(g[bir + 6], g[bir + 7]);
          const uint32_t XL0 = (uint32_t)__shfl_xor((int)PL0, 32, 64);
          const uint32_t XL1 = (uint32_t)__shfl_xor((int)PL1, 32, 64);
          const uint32_t XH0 = (uint32_t)__shfl_xor((int)PH0, 32, 64);
          const uint32_t XH1 = (uint32_t)__shfl_xor((int)PH1, 32, 64);
          pf[kk] = h0 ? mk_frag(PL0, PL1, XL0, XL1)
                      : mk_frag(XH0, XH1, PH0, PH1);
        }

        // O^T += V^T P^T
#pragma unroll
        for (int kk = 0; kk < 4; ++kk) {
          const bf16x8 vf0 = *(const bf16x8*)&Vc[l31 * 72 + kk * 16 + hi * 8];
          const bf16x8 vf1 =
              *(const bf16x8*)&Vc[(32 + l31) * 72 + kk * 16 + hi * 8];
          acc_t0 = mfma32(vf0, pf[kk], acc_t0);
          acc_t1 = mfma32(vf1, pf[kk], acc_t1);
        }
      }
    }

    // epilogue: partial l (own + partner half) -> Lg; unnormalized O^T -> O
    const float lt = lsum + __shfl_xor(lsum, 32, 64);
    if (h0) Lp[q0 + 32 * wave + l31] = lt;
    bf16_t* Ow = &Qs[(32 * wave) * 64];   // wave-private 32 rows
#pragma unroll
    for (int a = 0; a < 4; ++a)
#pragma unroll
      for (int c = 0; c < 4; c += 2) {
        const int r = 4 * a + c;
        const int d = c + 8 * a + 4 * hi;
        *(uint32_t*)&Ow[l31 * 64 + d]      = pk2(acc_t0[r], acc_t0[r + 1]);
        *(uint32_t*)&Ow[l31 * 64 + d + 32] = pk2(acc_t1[r], acc_t1[r + 1]);
      }
    bf16_t* Op = Opar + ((size_t)b * SEQ + q0 + 32 * wave) * EMB
                      + (size_t)h * HD;
#pragma unroll
    for (int i = 0; i < 4; ++i) {
      const int id = lane + 64 * i;       // 256 chunks: 32 rows x 8 col8
      const int row = id >> 3, col8 = (id & 7) * 8;
      *(uint4*)(Op + (size_t)row * EMB + col8) =
          *(const uint4*)&Ow[row * 64 + col8];
    }
  }
}

// ---------------------------------------------------------------- combine
// ab = (Oe + Oo) / (le + lo), in place into Oe.
__global__ __launch_bounds__(256) void combine(
    bf16_t* __restrict__ Oe, const bf16_t* __restrict__ Oo,
    const float* __restrict__ Lg) {
  const long idx = ((long)blockIdx.x * 256 + threadIdx.x) * 8;
  const int row = (int)(idx >> 10);   // 0..4095
  const int col = (int)(idx & 1023);
  const int b = row >> 11, sg = row & 2047, h = col >> 6;
  const int li = (b * 16 + h) * 2048 + sg;
  const float inv = 1.f / (Lg[li] + Lg[32 * 2048 + li]);
  const bf16x8 e = *(const bf16x8*)(Oe + idx);
  const bf16x8 o = *(const bf16x8*)(Oo + idx);
  bf16x8 rr;
#pragma unroll
  for (int u = 0; u < 8; ++u)
    rr[u] = (bf16_t)(((float)e[u] + (float)o[u]) * inv);
  *(bf16x8*)(Oe + idx) = rr;
}

// ---------------------------------------------------------------- launch
extern "C" void kernel_launch(void* const* d_in, const int* in_sizes, int n_in,
                              void* d_out, int out_size, void* d_ws,
                              size_t ws_size, hipStream_t stream) {
  const float* x  = (const float*)d_in[0];
  const float* Wq = (const float*)d_in[1];
  const float* bq = (const float*)d_in[2];
  const float* Wk = (const float*)d_in[3];
  const float* bk = (const float*)d_in[4];
  const float* Wv = (const float*)d_in[5];
  const float* bv = (const float*)d_in[6];
  const float* Wo = (const float*)d_in[7];
  const float* bo = (const float*)d_in[8];
  float* out = (float*)d_out;

  char* p = (char*)d_ws;
  bf16_t* xb   = (bf16_t*)p; p += (size_t)NX * 2;   // reused as VT after QKV
  bf16_t* wqb  = (bf16_t*)p; p += (size_t)NW * 2;   // wq/wk/wv contiguous
  bf16_t* wkb  = (bf16_t*)p; p += (size_t)NW * 2;
  bf16_t* wvb  = (bf16_t*)p; p += (size_t)NW * 2;
  bf16_t* wob  = (bf16_t*)p; p += (size_t)NW * 2;
  bf16_t* qkvb = (bf16_t*)p; p += (size_t)NX * 3 * 2;  // [4096][3072]
  bf16_t* ab   = (bf16_t*)p; p += (size_t)NX * 2;      // Oe, combined in place
  bf16_t* oob  = (bf16_t*)p; p += (size_t)NX * 2;      // Oo partial
  float*  lb   = (float*)p;  p += (size_t)2 * 32 * 2048 * 4;
  bf16_t* vtb  = xb;   // xb is dead after the QKV GEMM

  const int ntot = NX + 4 * NW;
  cvt_all<<<dim3(ntot / 4 / 256), 256, 0, stream>>>(
      x, Wq, Wk, Wv, Wo, xb, wqb, wkb, wvb, wob);

  gemm_f<bf16_t, 128, 128, QS>
      <<<dim3(QS / 128, MTOT / 128), 256, 0, stream>>>(
          xb, wqb, bq, bk, bv, qkvb);

  vtrans<<<dim3(BATCH * NH, SEQ / 64), 256, 0, stream>>>(qkvb, vtb);

  attn128<<<dim3(BATCH * NH, 8, 2), 256, 0, stream>>>(qkvb, vtb, ab, oob, lb);

  combine<<<dim3(NX / 8 / 256), 256, 0, stream>>>(ab, oob, lb);

  gemm_f<float, 64, 64, EMB>
      <<<dim3(EMB / 64, MTOT / 64), 256, 0, stream>>>(
          ab, wob, bo, bo, bo, out);
}